// Round 1
// baseline (192.961 us; speedup 1.0000x reference)
//
#include <hip/hip_runtime.h>

#define NPATH 16384
#define DIM   8
#define NINC  (NPATH - 1)        // 16383 increments / output rows
#define SIG   4680               // 8 + 64 + 512 + 4096
#define L1OFF 0
#define L2OFF 8
#define L3OFF 72
#define L4OFF 584
#define NBLK  256                // phase-1/3 blocks (chunks)
#define CHUNK 64                 // increments per chunk (256*64 = 16384 >= 16383)
#define NGRP  16                 // groups of chunks
#define GSIZE 16                 // chunks per group
#define C6    0.16666666666666666f

struct Sbuf { float a1[8]; float a2[64]; float z[8]; };

__device__ __forceinline__ void light_barrier() {
  // barrier that waits LDS ops only (not the in-flight global output stores)
  asm volatile("s_waitcnt lgkmcnt(0)" ::: "memory");
  __builtin_amdgcn_s_barrier();
}

// ---- load a full signature from global into (regs r4/r3) + A->a1/a2 (LDS) ----
__device__ __forceinline__ void load_sig_to_a(const float* __restrict__ src,
                                              float r4[16], float r3[2],
                                              Sbuf* A, int t) {
#pragma unroll
  for (int l = 0; l < 16; ++l) r4[l] = src[L4OFF + 16 * t + l];
  r3[0] = src[L3OFF + 2 * t];
  r3[1] = src[L3OFF + 2 * t + 1];
  if (t < 64) A->a2[t] = src[L2OFF + t];
  if (t < 8)  A->a1[t] = src[L1OFF + t];
}

// ---- store signature (regs + A) to global; caller guarantees A is sync-stable ----
__device__ __forceinline__ void store_sig(float* __restrict__ dst,
                                          const float r4[16], const float r3[2],
                                          const Sbuf* A, int t) {
#pragma unroll
  for (int l = 0; l < 16; ++l) dst[L4OFF + 16 * t + l] = r4[l];
  dst[L3OFF + 2 * t]     = r3[0];
  dst[L3OFF + 2 * t + 1] = r3[1];
  if (t < 64) dst[L2OFF + t] = A->a2[t];
  if (t < 8)  dst[L1OFF + t] = A->a1[t];
}

// ---- global -> LDS copy of one signature ----
__device__ __forceinline__ void load_lds_sig(float* sB, const float* __restrict__ src, int t) {
  const float4* s4 = (const float4*)src;
  float4* d4 = (float4*)sB;
  for (int idx = t; idx < SIG / 4; idx += 256) d4[idx] = s4[idx];
}

// ---- general Chen product: a (r4/r3 + A) = a o b (b staged in sB) ----
// Entry: caller has sync'd; A and sB valid. Exit: sync'd, A updated.
__device__ __forceinline__ void chen_general(float r4[16], float r3[2],
                                             Sbuf* A, const float* sB, int t) {
  const int i  = t >> 5;
  const int ij = t >> 2;
  const int c0 = 2 * t;
  const float a1i = A->a1[i];
  const float a2v = A->a2[ij];
  const float* b1 = sB + L1OFF;
  const float* b2 = sB + L2OFF;
  const float* b3 = sB + L3OFF;
  const float* b4 = sB + L4OFF;
  float b1r[8];
#pragma unroll
  for (int l = 0; l < 8; ++l) b1r[l] = b1[l];
#pragma unroll
  for (int u = 0; u < 2; ++u) {
    const int c  = c0 + u;
    const int jk = c & 63;
    const int k  = c & 7;
    const float a3c = r3[u];
#pragma unroll
    for (int l = 0; l < 8; ++l) {
      r4[u * 8 + l] += b4[c * 8 + l] + a1i * b3[jk * 8 + l] + a2v * b2[k * 8 + l] + a3c * b1r[l];
    }
    r3[u] += b3[c] + a1i * b2[jk] + a2v * b1[k];
  }
  float a2n = 0.f, a1n = 0.f;
  if (t < 64) a2n = A->a2[t] + b2[t] + A->a1[t >> 3] * b1[t & 7];
  if (t < 8)  a1n = A->a1[t] + b1[t];
  __syncthreads();
  if (t < 64) A->a2[t] = a2n;
  if (t < 8)  A->a1[t] = a1n;
  __syncthreads();
}

// ---- the cheap exp-Chen step loop (Horner form), double-buffered small state ----
// Entry: buf[p] holds {a1,a2,z for step 0}; znow regs hold z for step 0; barrier passed.
template <bool STORE>
__device__ __forceinline__ void run_steps(const float* __restrict__ path,
                                          float* __restrict__ out,
                                          int base, int nsteps,
                                          float r4[16], float r3[2],
                                          Sbuf* buf, int& p, float znow[8]) {
  const int t  = threadIdx.x;
  const int i  = t >> 5;
  const int j  = (t >> 2) & 7;
  const int k0 = 2 * (t & 3);
  const int k1 = k0 + 1;
  const int ij = t >> 2;
  const int i2 = t >> 3;
  const int j2 = t & 7;
  for (int s = 0; s < nsteps; ++s) {
    const int row = base + s;
    Sbuf* P = &buf[p];
    Sbuf* Q = &buf[p ^ 1];
    // uniform loads of NEXT step's increment (clamped at path end; unused then)
    const int rA = min(row + 1, NPATH - 1);
    const int rB = min(row + 2, NPATH - 1);
    float znext[8];
#pragma unroll
    for (int l = 0; l < 8; ++l) znext[l] = path[rB * DIM + l] - path[rA * DIM + l];
    // runtime-indexed reads of old small state (LDS)
    const float zi  = P->z[i];
    const float zj  = P->z[j];
    const float zk0 = P->z[k0];
    const float zk1 = P->z[k1];
    const float a1i = P->a1[i];
    const float a2v = P->a2[ij];
    // Horner factors
    const float a1zi4 = a1i + 0.25f * zi;
    const float zj6   = C6 * zj;
    const float T0 = r3[0] + a2v * (0.5f * zk0) + a1zi4 * (zj6 * zk0);
    const float T1 = r3[1] + a2v * (0.5f * zk1) + a1zi4 * (zj6 * zk1);
    const float U  = a2v + (0.5f * a1i + C6 * zi) * zj;
#pragma unroll
    for (int l = 0; l < 8; ++l) {
      r4[l]     += T0 * znow[l];
      r4[8 + l] += T1 * znow[l];
    }
    r3[0] += zk0 * U;
    r3[1] += zk1 * U;
    float a2n = 0.f, a1n = 0.f;
    if (t < 64) a2n = P->a2[t] + (P->a1[i2] + 0.5f * P->z[i2]) * P->z[j2];
    if (t < 8)  a1n = P->a1[t] + P->z[t];
    // publish new small state into the other buffer (no hazard with P reads)
    if (t < 64) Q->a2[t] = a2n;
    if (t < 8)  Q->a1[t] = a1n;
    if (t == 0) {
#pragma unroll
      for (int l = 0; l < 8; ++l) Q->z[l] = znext[l];
    }
    if constexpr (STORE) {
      float* dst = out + (size_t)row * SIG;
#pragma unroll
      for (int l = 0; l < 16; ++l) dst[L4OFF + 16 * t + l] = r4[l];
      dst[L3OFF + 2 * t]     = r3[0];
      dst[L3OFF + 2 * t + 1] = r3[1];
      if (t < 64) dst[L2OFF + t] = a2n;
      if (t < 8)  dst[L1OFF + t] = a1n;
    }
    light_barrier();
#pragma unroll
    for (int l = 0; l < 8; ++l) znow[l] = znext[l];
    p ^= 1;
  }
}

// ================= K1: per-chunk totals =================
__global__ __launch_bounds__(256) void k_chunk_totals(const float* __restrict__ path,
                                                      float* __restrict__ totals) {
  __shared__ Sbuf buf[2];
  const int t = threadIdx.x;
  const int b = blockIdx.x;
  const int base = b * CHUNK;
  const int n = min(CHUNK, NINC - base);
  float r4[16];
#pragma unroll
  for (int l = 0; l < 16; ++l) r4[l] = 0.f;
  float r3[2] = {0.f, 0.f};
  if (t < 64) buf[0].a2[t] = 0.f;
  if (t < 8)  buf[0].a1[t] = 0.f;
  float znow[8];
#pragma unroll
  for (int l = 0; l < 8; ++l) znow[l] = path[(base + 1) * DIM + l] - path[base * DIM + l];
  if (t == 0) {
#pragma unroll
    for (int l = 0; l < 8; ++l) buf[0].z[l] = znow[l];
  }
  __syncthreads();
  int p = 0;
  run_steps<false>(path, nullptr, base, n, r4, r3, buf, p, znow);
  store_sig(totals + (size_t)b * SIG, r4, r3, &buf[p], t);
}

// ================= K2/K3: sequential scan of `count` signatures per block =================
__global__ __launch_bounds__(256) void k_scan(const float* __restrict__ in,
                                              float* __restrict__ prefout,
                                              float* __restrict__ totout,
                                              int count) {
  __shared__ Sbuf A;
  __shared__ __align__(16) float sB[SIG];
  const int t = threadIdx.x;
  const size_t goff = (size_t)blockIdx.x * count;
  float r4[16];
#pragma unroll
  for (int l = 0; l < 16; ++l) r4[l] = 0.f;
  float r3[2] = {0.f, 0.f};
  if (t < 64) A.a2[t] = 0.f;
  if (t < 8)  A.a1[t] = 0.f;
  __syncthreads();
  for (int m = 0; m < count; ++m) {
    load_lds_sig(sB, in + (goff + m) * SIG, t);
    store_sig(prefout + (goff + m) * SIG, r4, r3, &A, t);  // exclusive prefix
    __syncthreads();                                        // sB ready; prefix reads done
    chen_general(r4, r3, &A, sB, t);                        // ends sync'd
  }
  if (totout != nullptr) store_sig(totout + (size_t)blockIdx.x * SIG, r4, r3, &A, t);
}

// ================= K5: apply prefixes, replay chunk, stream all rows =================
__global__ __launch_bounds__(256) void k_phase3(const float* __restrict__ path,
                                                const float* __restrict__ pref,
                                                const float* __restrict__ gpref,
                                                float* __restrict__ out) {
  __shared__ Sbuf buf[2];
  __shared__ __align__(16) float sB[SIG];
  const int t = threadIdx.x;
  const int b = blockIdx.x;
  const int g = b >> 4;  // GSIZE = 16
  const int base = b * CHUNK;
  const int n = min(CHUNK, NINC - base);
  float r4[16];
  float r3[2];
  load_sig_to_a(gpref + (size_t)g * SIG, r4, r3, &buf[0], t);
  load_lds_sig(sB, pref + (size_t)b * SIG, t);
  __syncthreads();
  chen_general(r4, r3, &buf[0], sB, t);  // a = gpref[g] o pref[b]  (exclusive chunk prefix)
  float znow[8];
#pragma unroll
  for (int l = 0; l < 8; ++l) znow[l] = path[(base + 1) * DIM + l] - path[base * DIM + l];
  if (t == 0) {
#pragma unroll
    for (int l = 0; l < 8; ++l) buf[0].z[l] = znow[l];
  }
  __syncthreads();
  int p = 0;
  run_steps<true>(path, out, base, n, r4, r3, buf, p, znow);
}

extern "C" void kernel_launch(void* const* d_in, const int* in_sizes, int n_in,
                              void* d_out, int out_size, void* d_ws, size_t ws_size,
                              hipStream_t stream) {
  (void)in_sizes; (void)n_in; (void)out_size; (void)ws_size;
  const float* path = (const float*)d_in[0];
  float* out = (float*)d_out;
  float* ws = (float*)d_ws;

  float* totals = ws;                              // 256 * 4680
  float* pref   = totals + (size_t)NBLK * SIG;     // 256 * 4680
  float* gtot   = pref   + (size_t)NBLK * SIG;     // 16 * 4680
  float* gpref  = gtot   + (size_t)NGRP * SIG;     // 16 * 4680

  k_chunk_totals<<<NBLK, 256, 0, stream>>>(path, totals);
  k_scan<<<NGRP, 256, 0, stream>>>(totals, pref, gtot, GSIZE);
  k_scan<<<1, 256, 0, stream>>>(gtot, gpref, nullptr, NGRP);
  k_phase3<<<NBLK, 256, 0, stream>>>(path, pref, gpref, out);
}

// Round 2
// 153.853 us; speedup vs baseline: 1.2542x; 1.2542x over previous
//
#include <hip/hip_runtime.h>

#define NPATH 16384
#define DIM   8
#define NINC  (NPATH - 1)        // 16383 increments / output rows
#define SIG   4680               // 8 + 64 + 512 + 4096
#define L1OFF 0
#define L2OFF 8
#define L3OFF 72
#define L4OFF 584
#define NBLK  256                // phase-1/3 blocks (chunks)
#define CHUNK 64                 // increments per chunk (256*64 = 16384 >= 16383)
#define NGRP  16                 // groups of chunks
#define GSIZE 16                 // chunks per group
#define C6    0.16666666666666666f

// Per-thread register state (t = threadIdx.x, 256 threads):
//   r4[16] : level-4 elements 16t..16t+15  (rows c0=2t, c1=2t+1 of [512][8])
//   r3[2]  : level-3 elements 2t, 2t+1
//   a1i    : a1[i],  i  = t>>5      (consumed by level-3/4 updates)
//   a2v    : a2[ij], ij = t>>2      (consumed by level-3/4 updates)
//   a2s    : a2[t]   (t<64)         (store/output mapping)
//   a1s    : a1[t>>3] (t<64)        (feeds a2s update)
//   a1t    : a1[t]   (t<8)          (store/output mapping)
// No LDS state, no barriers in any inner loop.

// ---- store full signature from registers ----
__device__ __forceinline__ void store_sig_reg(float* __restrict__ dst,
                                              const float r4[16], const float r3[2],
                                              float a2s, float a1t, int t) {
  float4* d4 = (float4*)(dst + L4OFF + 16 * t);
  d4[0] = make_float4(r4[0], r4[1], r4[2], r4[3]);
  d4[1] = make_float4(r4[4], r4[5], r4[6], r4[7]);
  d4[2] = make_float4(r4[8], r4[9], r4[10], r4[11]);
  d4[3] = make_float4(r4[12], r4[13], r4[14], r4[15]);
  *(float2*)(dst + L3OFF + 2 * t) = make_float2(r3[0], r3[1]);
  if (t < 64) dst[L2OFF + t] = a2s;
  if (t < 8)  dst[L1OFF + t] = a1t;
}

// ---- general Chen product, b read directly from global (no LDS, no barrier) ----
__device__ __forceinline__ void chen_reg(float r4[16], float r3[2],
                                         float& a1i, float& a2v,
                                         float& a2s, float& a1s, float& a1t,
                                         const float* __restrict__ b, int t) {
  const int i   = t >> 5;
  const int j   = (t >> 2) & 7;
  const int ij  = t >> 2;
  const int c0  = 2 * t;
  const int jk0 = c0 & 63;          // even; jk1 = jk0+1
  const int k0  = 2 * (t & 3);      // even; k1 = k0+1
  const int i2  = t >> 3;
  const int j2  = t & 7;
  const float4* bv = (const float4*)b;
  // b4 row pair (16 floats, 64B): floats L4OFF + 16t
  float4 B0 = bv[146 + 4 * t], B1 = bv[147 + 4 * t], B2 = bv[148 + 4 * t], B3 = bv[149 + 4 * t];
  // b3 rows jk0, jk0+1 (16 floats): floats L3OFF + 8*jk0
  float4 Cq0 = bv[18 + 2 * jk0], Cq1 = bv[19 + 2 * jk0], Cq2 = bv[20 + 2 * jk0], Cq3 = bv[21 + 2 * jk0];
  // b2 rows k0, k0+1 (16 floats): floats L2OFF + 8*k0
  float4 D0 = bv[2 + 2 * k0], D1 = bv[3 + 2 * k0], D2 = bv[4 + 2 * k0], D3 = bv[5 + 2 * k0];
  // b1 full row (uniform)
  float4 E0 = bv[0], E1 = bv[1];
  // scalars
  const float2 b3c  = *(const float2*)(b + L3OFF + c0);
  const float2 b2jk = *(const float2*)(b + L2OFF + jk0);
  const float2 b1k  = *(const float2*)(b + L1OFF + k0);
  const float b2ij = b[L2OFF + ij];
  const float b1j  = b[L1OFF + j];
  const float b1i  = b[L1OFF + i];
  float b2t = 0.f, b1j2 = 0.f, b1i2 = 0.f, b1t = 0.f;
  if (t < 64) { b2t = b[L2OFF + t]; b1j2 = b[L1OFF + j2]; b1i2 = b[L1OFF + i2]; }
  if (t < 8)  { b1t = b[L1OFF + t]; }

  const float b4r[16] = {B0.x,B0.y,B0.z,B0.w, B1.x,B1.y,B1.z,B1.w,
                         B2.x,B2.y,B2.z,B2.w, B3.x,B3.y,B3.z,B3.w};
  const float b3r[16] = {Cq0.x,Cq0.y,Cq0.z,Cq0.w, Cq1.x,Cq1.y,Cq1.z,Cq1.w,
                         Cq2.x,Cq2.y,Cq2.z,Cq2.w, Cq3.x,Cq3.y,Cq3.z,Cq3.w};
  const float b2r[16] = {D0.x,D0.y,D0.z,D0.w, D1.x,D1.y,D1.z,D1.w,
                         D2.x,D2.y,D2.z,D2.w, D3.x,D3.y,D3.z,D3.w};
  const float b1r[8]  = {E0.x,E0.y,E0.z,E0.w, E1.x,E1.y,E1.z,E1.w};

#pragma unroll
  for (int l = 0; l < 8; ++l) {
    r4[l]     += b4r[l]     + a1i * b3r[l]     + a2v * b2r[l]     + r3[0] * b1r[l];
    r4[8 + l] += b4r[8 + l] + a1i * b3r[8 + l] + a2v * b2r[8 + l] + r3[1] * b1r[l];
  }
  r3[0] += b3c.x + a1i * b2jk.x + a2v * b1k.x;
  r3[1] += b3c.y + a1i * b2jk.y + a2v * b1k.y;
  const float a1i_old = a1i;
  a2v += b2ij + a1i_old * b1j;
  if (t < 64) { a2s += b2t + a1s * b1j2; a1s += b1i2; }
  a1i = a1i_old + b1i;
  if (t < 8) a1t += b1t;
}

// ---- fill per-chunk increment table (2 KB LDS), then one sync ----
__device__ __forceinline__ void fill_zbuf(float (*zbuf)[8], const float* __restrict__ path,
                                          int base, int t) {
  for (int u = t; u < CHUNK * 8; u += 256) {
    const int s = u >> 3, l = u & 7;
    const int rB = min(base + s + 1, NPATH - 1);
    zbuf[s][l] = path[rB * DIM + l] - path[(base + s) * DIM + l];
  }
}

// ---- barrier-free exp-Chen step loop (Horner form), all-register state ----
template <bool STORE>
__device__ __forceinline__ void run_steps(const float (*zbuf)[8],
                                          float* __restrict__ out, int base, int nsteps,
                                          float r4[16], float r3[2],
                                          float& a1i, float& a2v,
                                          float& a2s, float& a1s, float& a1t, int t) {
  const int i  = t >> 5;
  const int j  = (t >> 2) & 7;
  const int k0 = 2 * (t & 3);
  const int i2 = t >> 3;
  const int j2 = t & 7;
  for (int s = 0; s < nsteps; ++s) {
    const float* zs = zbuf[s];
    const float zi = zs[i];
    const float zj = zs[j];
    const float2 zk = *(const float2*)(zs + k0);
    const float4 za = *(const float4*)zs;
    const float4 zb = *(const float4*)(zs + 4);
    const float zn[8] = {za.x, za.y, za.z, za.w, zb.x, zb.y, zb.z, zb.w};
    // Horner factors (use OLD a1i/a2v/r3)
    const float a1zi4 = a1i + 0.25f * zi;
    const float zj6   = C6 * zj;
    const float T0 = r3[0] + a2v * (0.5f * zk.x) + a1zi4 * (zj6 * zk.x);
    const float T1 = r3[1] + a2v * (0.5f * zk.y) + a1zi4 * (zj6 * zk.y);
    const float U  = a2v + (0.5f * a1i + C6 * zi) * zj;
#pragma unroll
    for (int l = 0; l < 8; ++l) {
      r4[l]     += T0 * zn[l];
      r4[8 + l] += T1 * zn[l];
    }
    r3[0] += zk.x * U;
    r3[1] += zk.y * U;
    a2v += (a1i + 0.5f * zi) * zj;
    a1i += zi;
    if (t < 64) {
      const float zi2 = zs[i2], zj2v = zs[j2];
      a2s += (a1s + 0.5f * zi2) * zj2v;
      a1s += zi2;
    }
    if (t < 8) a1t += zs[t];
    if constexpr (STORE) {
      float* dst = out + (size_t)(base + s) * SIG;
      float4* d4 = (float4*)(dst + L4OFF + 16 * t);
      d4[0] = make_float4(r4[0], r4[1], r4[2], r4[3]);
      d4[1] = make_float4(r4[4], r4[5], r4[6], r4[7]);
      d4[2] = make_float4(r4[8], r4[9], r4[10], r4[11]);
      d4[3] = make_float4(r4[12], r4[13], r4[14], r4[15]);
      *(float2*)(dst + L3OFF + 2 * t) = make_float2(r3[0], r3[1]);
      if (t < 64) dst[L2OFF + t] = a2s;
      if (t < 8)  dst[L1OFF + t] = a1t;
    }
  }
}

// ================= K1: per-chunk totals =================
__global__ __launch_bounds__(256) void k_chunk_totals(const float* __restrict__ path,
                                                      float* __restrict__ totals) {
  __shared__ float zbuf[CHUNK][8];
  const int t = threadIdx.x;
  const int b = blockIdx.x;
  const int base = b * CHUNK;
  const int n = min(CHUNK, NINC - base);
  fill_zbuf(zbuf, path, base, t);
  float r4[16];
#pragma unroll
  for (int l = 0; l < 16; ++l) r4[l] = 0.f;
  float r3[2] = {0.f, 0.f};
  float a1i = 0.f, a2v = 0.f, a2s = 0.f, a1s = 0.f, a1t = 0.f;
  __syncthreads();
  run_steps<false>(zbuf, nullptr, base, n, r4, r3, a1i, a2v, a2s, a1s, a1t, t);
  store_sig_reg(totals + (size_t)b * SIG, r4, r3, a2s, a1t, t);
}

// ================= K2/K3: sequential scan of `count` signatures per block =================
__global__ __launch_bounds__(256) void k_scan(const float* __restrict__ in,
                                              float* __restrict__ prefout,
                                              float* __restrict__ totout,
                                              int count) {
  const int t = threadIdx.x;
  const size_t goff = (size_t)blockIdx.x * count;
  float r4[16];
#pragma unroll
  for (int l = 0; l < 16; ++l) r4[l] = 0.f;
  float r3[2] = {0.f, 0.f};
  float a1i = 0.f, a2v = 0.f, a2s = 0.f, a1s = 0.f, a1t = 0.f;
  for (int m = 0; m < count; ++m) {
    store_sig_reg(prefout + (goff + m) * SIG, r4, r3, a2s, a1t, t);   // exclusive prefix
    chen_reg(r4, r3, a1i, a2v, a2s, a1s, a1t, in + (goff + m) * SIG, t);
  }
  if (totout != nullptr) store_sig_reg(totout + (size_t)blockIdx.x * SIG, r4, r3, a2s, a1t, t);
}

// ================= K5: apply prefixes, replay chunk, stream all rows =================
__global__ __launch_bounds__(256) void k_phase3(const float* __restrict__ path,
                                                const float* __restrict__ pref,
                                                const float* __restrict__ gpref,
                                                float* __restrict__ out) {
  __shared__ float zbuf[CHUNK][8];
  const int t = threadIdx.x;
  const int b = blockIdx.x;
  const int g = b >> 4;  // GSIZE = 16
  const int base = b * CHUNK;
  const int n = min(CHUNK, NINC - base);
  fill_zbuf(zbuf, path, base, t);
  // load group prefix into register state
  const float* gp = gpref + (size_t)g * SIG;
  const float4* g4 = (const float4*)(gp + L4OFF + 16 * t);
  float4 G0 = g4[0], G1 = g4[1], G2 = g4[2], G3 = g4[3];
  float r4[16] = {G0.x,G0.y,G0.z,G0.w, G1.x,G1.y,G1.z,G1.w,
                  G2.x,G2.y,G2.z,G2.w, G3.x,G3.y,G3.z,G3.w};
  const float2 gr3 = *(const float2*)(gp + L3OFF + 2 * t);
  float r3[2] = {gr3.x, gr3.y};
  float a1i = gp[L1OFF + (t >> 5)];
  float a2v = gp[L2OFF + (t >> 2)];
  float a2s = 0.f, a1s = 0.f, a1t = 0.f;
  if (t < 64) { a2s = gp[L2OFF + t]; a1s = gp[L1OFF + (t >> 3)]; }
  if (t < 8)  { a1t = gp[L1OFF + t]; }
  // a = gpref[g] o pref[b]  (exclusive chunk prefix)
  chen_reg(r4, r3, a1i, a2v, a2s, a1s, a1t, pref + (size_t)b * SIG, t);
  __syncthreads();  // zbuf ready
  run_steps<true>(zbuf, out, base, n, r4, r3, a1i, a2v, a2s, a1s, a1t, t);
}

extern "C" void kernel_launch(void* const* d_in, const int* in_sizes, int n_in,
                              void* d_out, int out_size, void* d_ws, size_t ws_size,
                              hipStream_t stream) {
  (void)in_sizes; (void)n_in; (void)out_size; (void)ws_size;
  const float* path = (const float*)d_in[0];
  float* out = (float*)d_out;
  float* ws = (float*)d_ws;

  float* totals = ws;                              // 256 * 4680
  float* pref   = totals + (size_t)NBLK * SIG;     // 256 * 4680
  float* gtot   = pref   + (size_t)NBLK * SIG;     // 16 * 4680
  float* gpref  = gtot   + (size_t)NGRP * SIG;     // 16 * 4680

  k_chunk_totals<<<NBLK, 256, 0, stream>>>(path, totals);
  k_scan<<<NGRP, 256, 0, stream>>>(totals, pref, gtot, GSIZE);
  k_scan<<<1, 256, 0, stream>>>(gtot, gpref, nullptr, NGRP);
  k_phase3<<<NBLK, 256, 0, stream>>>(path, pref, gpref, out);
}